// Round 1
// baseline (337.074 us; speedup 1.0000x reference)
//
#include <hip/hip_runtime.h>
#include <hip/hip_bf16.h>

// LinearAttentionTriton: out_t = Q_t @ (K_t^T @ V_t) @ S,  S = V^T K (fp32)
// N = 262144, D = 64, TRUNK = 128, fp32 in/out.

#define TRUNK 128
#define DD 64

typedef __bf16 bf16x8 __attribute__((ext_vector_type(8)));
typedef float  f32x4  __attribute__((ext_vector_type(4)));
typedef unsigned int   u32;
typedef unsigned short u16;
typedef u32 u32x4 __attribute__((ext_vector_type(4)));
typedef u32 u32x2 __attribute__((ext_vector_type(2)));

union F8 { bf16x8 v; u16 u[8]; u32x4 q; };

__device__ __forceinline__ u16 f2bf(float x) {
    union { float f; u32 u; } a; a.f = x;
    u32 u = a.u;
    return (u16)((u + 0x7FFFu + ((u >> 16) & 1u)) >> 16);
}
__device__ __forceinline__ u32 pack2(float a, float b) {
    return (u32)f2bf(a) | ((u32)f2bf(b) << 16);
}

// ---------------- Kernel A: S = V^T K (fp32, atomicAdd into ws) -------------
// 1024 blocks x 256 threads; each block reduces 256 rows; thread owns 4x4 tile.
__global__ __launch_bounds__(256) void s_kernel(const float* __restrict__ K,
                                                const float* __restrict__ V,
                                                float* __restrict__ S) {
    __shared__ __align__(16) float Vc[32 * 64];
    __shared__ __align__(16) float Kc[32 * 64];
    const int t  = threadIdx.x;
    const int ty = t >> 4;      // dv = 4*ty
    const int tx = t & 15;      // dk = 4*tx
    const long base = (long)blockIdx.x * 256 * 64;

    float acc[4][4] = {};
    for (int chunk = 0; chunk < 8; ++chunk) {
        const long cb = base + (long)chunk * 32 * 64;
        #pragma unroll
        for (int i = 0; i < 2; ++i) {
            int f4 = i * 256 + t;                 // 512 float4 per 32x64 chunk
            float4 v = ((const float4*)(V + cb))[f4];
            float4 k = ((const float4*)(K + cb))[f4];
            ((float4*)Vc)[f4] = v;
            ((float4*)Kc)[f4] = k;
        }
        __syncthreads();
        #pragma unroll 8
        for (int r = 0; r < 32; ++r) {
            float4 vv = ((const float4*)(Vc + r * 64))[ty];
            float4 kk = ((const float4*)(Kc + r * 64))[tx];
            const float* vp = (const float*)&vv;
            const float* kp = (const float*)&kk;
            #pragma unroll
            for (int a = 0; a < 4; ++a)
                #pragma unroll
                for (int b = 0; b < 4; ++b)
                    acc[a][b] += vp[a] * kp[b];
        }
        __syncthreads();
    }
    #pragma unroll
    for (int a = 0; a < 4; ++a)
        #pragma unroll
        for (int b = 0; b < 4; ++b)
            atomicAdd(&S[(4 * ty + a) * 64 + (4 * tx + b)], acc[a][b]);
}

// ---------------- Kernel B: per-trunk  out = Q (K^T V) S --------------------
// One trunk (128 rows) per 256-thread block. bf16 MFMA 16x16x32, fp32 accum.
// LDS strides: K/V = 66 (conflict-free u16 column reads); G/HT/ST = 72
// (balanced, 16B-aligned b128 row reads). G/HT overlay dead K/V space.
#define KV_S 66
#define P_S  72
#define KB_OFF 0            // [128][66] = 8448
#define VB_OFF 8448         // [128][66]
#define ST_OFF 16896        // [64][72]  ST[c][b] = S[b][c]
#define G_OFF  0            // [64][72]  G[a][b] = sum_r K[r][a] V[r][b]
#define HT_OFF 4608         // [64][72]  HT[c][a] = H[a][c],  H = G @ S
#define LDS_ELEMS 21504     // 43008 bytes -> 3 blocks/CU

__global__ __launch_bounds__(256, 3) void trunk_kernel(const float* __restrict__ Q,
                                                       const float* __restrict__ K,
                                                       const float* __restrict__ V,
                                                       const float* __restrict__ S,
                                                       float* __restrict__ out) {
    __shared__ __align__(16) u16 lds[LDS_ELEMS];
    u16* Kb  = lds + KB_OFF;
    u16* Vb  = lds + VB_OFF;
    u16* STb = lds + ST_OFF;
    u16* Gb  = lds + G_OFF;
    u16* HTb = lds + HT_OFF;

    const int t    = threadIdx.x;
    const int lane = t & 63;
    const int wave = t >> 6;
    const int l15  = lane & 15;
    const int quad = lane >> 4;
    const long tb  = (long)blockIdx.x * (TRUNK * DD);

    // ---- stage K,V -> bf16 LDS (natural layout, stride 66); S -> ST bf16 ----
    for (int i = 0; i < 8; ++i) {
        int f4 = i * 256 + t;                  // float4 index, 2048 per matrix
        int r = f4 >> 4, c = (f4 & 15) << 2;
        float4 kv = ((const float4*)(K + tb))[f4];
        float4 vv = ((const float4*)(V + tb))[f4];
        *(u32*)&Kb[r * KV_S + c]     = pack2(kv.x, kv.y);
        *(u32*)&Kb[r * KV_S + c + 2] = pack2(kv.z, kv.w);
        *(u32*)&Vb[r * KV_S + c]     = pack2(vv.x, vv.y);
        *(u32*)&Vb[r * KV_S + c + 2] = pack2(vv.z, vv.w);
    }
    for (int i = 0; i < 4; ++i) {
        int f4 = i * 256 + t;                  // 1024 float4 of S (64x64 fp32)
        int b = f4 >> 4, c = (f4 & 15) << 2;
        float4 s4 = ((const float4*)S)[f4];
        STb[(c + 0) * P_S + b] = f2bf(s4.x);
        STb[(c + 1) * P_S + b] = f2bf(s4.y);
        STb[(c + 2) * P_S + b] = f2bf(s4.z);
        STb[(c + 3) * P_S + b] = f2bf(s4.w);
    }
    __syncthreads();

    // ---- stage 1: C1 = V^T K (m = V-col b, n = K-col a, k = row r) ----------
    const int mt0 = (wave >> 1) << 1;          // 2x2 tile quadrant per wave
    const int nt0 = (wave & 1) << 1;
    f32x4 gacc[2][2] = {};
    #pragma unroll
    for (int kt = 0; kt < 4; ++kt) {
        const int rbase = kt * 32 + quad * 8;
        F8 af[2], bf[2];
        #pragma unroll
        for (int mi = 0; mi < 2; ++mi) {
            const int bcol = (mt0 + mi) * 16 + l15;     // V column (b)
            #pragma unroll
            for (int j = 0; j < 8; ++j) af[mi].u[j] = Vb[(rbase + j) * KV_S + bcol];
        }
        #pragma unroll
        for (int ni = 0; ni < 2; ++ni) {
            const int acol = (nt0 + ni) * 16 + l15;     // K column (a)
            #pragma unroll
            for (int j = 0; j < 8; ++j) bf[ni].u[j] = Kb[(rbase + j) * KV_S + acol];
        }
        #pragma unroll
        for (int mi = 0; mi < 2; ++mi)
            #pragma unroll
            for (int ni = 0; ni < 2; ++ni)
                gacc[mi][ni] = __builtin_amdgcn_mfma_f32_16x16x32_bf16(
                    af[mi].v, bf[ni].v, gacc[mi][ni], 0, 0, 0);
    }
    __syncthreads();   // all K/V reads done before overlaying G/HT

    // C1[b][a] = G[a][b]; C-frag: row=4*quad+reg, col=l15. Write G natural:
    // G[a = 16*(nt0+ni)+l15][b = 16*(mt0+mi)+4*quad + reg] -> 4 contiguous bf16
    #pragma unroll
    for (int mi = 0; mi < 2; ++mi)
        #pragma unroll
        for (int ni = 0; ni < 2; ++ni) {
            const int ga  = (nt0 + ni) * 16 + l15;
            const int gb0 = (mt0 + mi) * 16 + quad * 4;
            const float* g = (const float*)&gacc[mi][ni];
            u32x2 w; w[0] = pack2(g[0], g[1]); w[1] = pack2(g[2], g[3]);
            *(u32x2*)&Gb[ga * P_S + gb0] = w;
        }
    __syncthreads();

    // ---- stage 2: H = G @ S  (A = G rows, B = ST rows) ----------------------
    f32x4 hacc[2][2] = {};
    #pragma unroll
    for (int kt = 0; kt < 2; ++kt) {
        const int kb = kt * 32 + quad * 8;
        F8 a2[2], b2[2];
        #pragma unroll
        for (int mi = 0; mi < 2; ++mi)
            a2[mi].q = *(const u32x4*)&Gb[((mt0 + mi) * 16 + l15) * P_S + kb];
        #pragma unroll
        for (int ni = 0; ni < 2; ++ni)
            b2[ni].q = *(const u32x4*)&STb[((nt0 + ni) * 16 + l15) * P_S + kb];
        #pragma unroll
        for (int mi = 0; mi < 2; ++mi)
            #pragma unroll
            for (int ni = 0; ni < 2; ++ni)
                hacc[mi][ni] = __builtin_amdgcn_mfma_f32_16x16x32_bf16(
                    a2[mi].v, b2[ni].v, hacc[mi][ni], 0, 0, 0);
    }
    // write HT[c][a] (HT region disjoint from G/ST; no barrier needed first)
    #pragma unroll
    for (int mi = 0; mi < 2; ++mi)
        #pragma unroll
        for (int ni = 0; ni < 2; ++ni) {
            const int hc  = (nt0 + ni) * 16 + l15;
            const int ha0 = (mt0 + mi) * 16 + quad * 4;
            const float* h = (const float*)&hacc[mi][ni];
            u32x2 w; w[0] = pack2(h[0], h[1]); w[1] = pack2(h[2], h[3]);
            *(u32x2*)&HTb[hc * P_S + ha0] = w;
        }
    __syncthreads();

    // ---- stage 3: out = Q @ H  (A = Q from global, B = HT rows) -------------
    f32x4 oacc[2][4] = {};
    #pragma unroll
    for (int kt = 0; kt < 2; ++kt) {
        const int ka = kt * 32 + quad * 8;
        F8 a3[2];
        #pragma unroll
        for (int mi = 0; mi < 2; ++mi) {
            const int r = (wave * 2 + mi) * 16 + l15;
            const float* qp = Q + tb + r * 64 + ka;
            float4 q0 = *(const float4*)(qp);
            float4 q1 = *(const float4*)(qp + 4);
            a3[mi].q[0] = pack2(q0.x, q0.y);
            a3[mi].q[1] = pack2(q0.z, q0.w);
            a3[mi].q[2] = pack2(q1.x, q1.y);
            a3[mi].q[3] = pack2(q1.z, q1.w);
        }
        #pragma unroll
        for (int ni = 0; ni < 4; ++ni) {
            F8 bb;
            bb.q = *(const u32x4*)&HTb[(ni * 16 + l15) * P_S + ka];
            #pragma unroll
            for (int mi = 0; mi < 2; ++mi)
                oacc[mi][ni] = __builtin_amdgcn_mfma_f32_16x16x32_bf16(
                    a3[mi].v, bb.v, oacc[mi][ni], 0, 0, 0);
        }
    }
    #pragma unroll
    for (int mi = 0; mi < 2; ++mi)
        #pragma unroll
        for (int ni = 0; ni < 4; ++ni) {
            const int row0 = (wave * 2 + mi) * 16 + quad * 4;
            const int col  = ni * 16 + l15;
            const float* o = (const float*)&oacc[mi][ni];
            #pragma unroll
            for (int reg = 0; reg < 4; ++reg)
                out[tb + (long)(row0 + reg) * 64 + col] = o[reg];
        }
}

extern "C" void kernel_launch(void* const* d_in, const int* in_sizes, int n_in,
                              void* d_out, int out_size, void* d_ws, size_t ws_size,
                              hipStream_t stream) {
    const float* Q = (const float*)d_in[0];
    const float* K = (const float*)d_in[1];
    const float* V = (const float*)d_in[2];
    float* out = (float*)d_out;
    float* S   = (float*)d_ws;                 // 64*64 fp32 = 16 KB scratch

    const int n = in_sizes[0] / DD;            // 262144 rows
    hipMemsetAsync(S, 0, DD * DD * sizeof(float), stream);
    s_kernel<<<n / 256, 256, 0, stream>>>(K, V, S);
    trunk_kernel<<<n / TRUNK, 256, 0, stream>>>(Q, K, V, S, out);
}

// Round 4
// 240.935 us; speedup vs baseline: 1.3990x; 1.3990x over previous
//
#include <hip/hip_runtime.h>
#include <hip/hip_bf16.h>

// LinearAttentionTriton: out_t = Q_t @ (K_t^T @ V_t) @ S,  S = V^T K (fp32)
// N = 262144, D = 64, TRUNK = 128, fp32 in/out.
//
// Round-2/3 bug (fixed here): K^T/V^T LDS staged at stride 72 but indexed by
// row (0..127) -> out-of-row aliasing. Transposed layout stride is now 136
// (272 B: 16B-aligned b128 fragment reads, row fits).
// ws usage capped at 16 KB (just S); S-partials live in the tail of d_out,
// consumed by s_reduce then overwritten by trunk_kernel (stream-serialized).

#define TRUNK 128
#define DD 64
#define NPART 512          // s_partial blocks; each covers 512 rows

typedef __bf16 bf16x8 __attribute__((ext_vector_type(8)));
typedef float  f32x4  __attribute__((ext_vector_type(4)));
typedef unsigned int   u32;
typedef unsigned short u16;
typedef u32 u32x4 __attribute__((ext_vector_type(4)));
typedef u32 u32x2 __attribute__((ext_vector_type(2)));

union F8 { bf16x8 v; u16 u[8]; u32x4 q; };

__device__ __forceinline__ u16 f2bf(float x) {
    union { float f; u32 u; } a; a.f = x;
    u32 u = a.u;
    return (u16)((u + 0x7FFFu + ((u >> 16) & 1u)) >> 16);
}
__device__ __forceinline__ u32 pack2(float a, float b) {
    return (u32)f2bf(a) | ((u32)f2bf(b) << 16);
}

#define P_S  72    // stride for 64x64 mats (G/HT/ST): 144 B rows
#define KV_T 136   // stride for transposed K^T/V^T (64 cols x 128 rows): 272 B

// Stage a 128x64 fp32 global tile as bf16 TRANSPOSED into LDS[64][KV_T].
// 512 work-items (2 iters of 256 thr): 4 rows x 4 cols each, ds_write_b64.
__device__ __forceinline__ void stage_T(const float* __restrict__ M, long tb,
                                        u16* __restrict__ MT, int t) {
    #pragma unroll
    for (int i = 0; i < 2; ++i) {
        int pid = i * 256 + t;          // [0,512)
        int rr = (pid >> 4) * 4;        // row group 0..124
        int c  = (pid & 15) * 4;        // col group 0..60
        float4 r0 = *(const float4*)(M + tb + (rr + 0) * 64 + c);
        float4 r1 = *(const float4*)(M + tb + (rr + 1) * 64 + c);
        float4 r2 = *(const float4*)(M + tb + (rr + 2) * 64 + c);
        float4 r3 = *(const float4*)(M + tb + (rr + 3) * 64 + c);
        const float* p0 = (const float*)&r0; const float* p1 = (const float*)&r1;
        const float* p2 = (const float*)&r2; const float* p3 = (const float*)&r3;
        #pragma unroll
        for (int j = 0; j < 4; ++j) {
            u32x2 w; w[0] = pack2(p0[j], p1[j]); w[1] = pack2(p2[j], p3[j]);
            *(u32x2*)&MT[(c + j) * KV_T + rr] = w;   // 8B, aligned (rr%4==0)
        }
    }
}

// ---------------- Kernel A: per-block MFMA partial of S = V^T K --------------
// 512 blocks x 256 threads; block accumulates V^T K over 4 x 128-row chunks
// in fp32 accumulators, writes one 64x64 fp32 partial. No atomics.
__global__ __launch_bounds__(256) void s_partial(const float* __restrict__ K,
                                                 const float* __restrict__ V,
                                                 float* __restrict__ P) {
    __shared__ __align__(16) u16 lds[2 * 64 * KV_T];
    u16* KT = lds;                  // [64][136]
    u16* VT = lds + 64 * KV_T;      // [64][136]

    const int t    = threadIdx.x;
    const int lane = t & 63;
    const int wave = t >> 6;
    const int l15  = lane & 15;
    const int quad = lane >> 4;
    const int mt0  = (wave >> 1) << 1;
    const int nt0  = (wave & 1) << 1;

    f32x4 gacc[2][2] = {};
    const long rowbase = (long)blockIdx.x * 512;

    for (int c = 0; c < 4; ++c) {
        const long tb = (rowbase + c * 128) * 64;
        stage_T(K, tb, KT, t);
        stage_T(V, tb, VT, t);
        __syncthreads();
        // C1[b][a] += sum_r V[r][b] K[r][a]  (A = V cols, B = K cols)
        #pragma unroll
        for (int kt = 0; kt < 4; ++kt) {
            const int rbase = kt * 32 + quad * 8;
            F8 af[2], bf[2];
            #pragma unroll
            for (int mi = 0; mi < 2; ++mi)
                af[mi].q = *(const u32x4*)&VT[((mt0 + mi) * 16 + l15) * KV_T + rbase];
            #pragma unroll
            for (int ni = 0; ni < 2; ++ni)
                bf[ni].q = *(const u32x4*)&KT[((nt0 + ni) * 16 + l15) * KV_T + rbase];
            #pragma unroll
            for (int mi = 0; mi < 2; ++mi)
                #pragma unroll
                for (int ni = 0; ni < 2; ++ni)
                    gacc[mi][ni] = __builtin_amdgcn_mfma_f32_16x16x32_bf16(
                        af[mi].v, bf[ni].v, gacc[mi][ni], 0, 0, 0);
        }
        __syncthreads();    // reads done before restaging next chunk
    }

    // write fp32 partial, natural S layout: C row=b (quad*4+reg), col=a (l15)
    float* o = P + (long)blockIdx.x * 4096;
    #pragma unroll
    for (int mi = 0; mi < 2; ++mi)
        #pragma unroll
        for (int ni = 0; ni < 2; ++ni) {
            const int b0 = (mt0 + mi) * 16 + quad * 4;
            const int a  = (nt0 + ni) * 16 + l15;
            const float* g = (const float*)&gacc[mi][ni];
            #pragma unroll
            for (int reg = 0; reg < 4; ++reg)
                o[(b0 + reg) * 64 + a] = g[reg];
        }
}

// ---------------- Kernel A2: reduce 512 partials -> S (fp32) ----------------
// 8192 threads = 1024 float4-groups x 8 ways; 8 atomics/address. S pre-zeroed.
__global__ __launch_bounds__(256) void s_reduce(const float* __restrict__ P,
                                                float* __restrict__ S) {
    const int tid = blockIdx.x * 256 + threadIdx.x;  // [0, 8192)
    const int eg  = tid & 1023;                       // float4 group of S
    const int way = tid >> 10;                        // [0, 8)
    const float4* p = (const float4*)P;
    float4 acc = {0.f, 0.f, 0.f, 0.f};
    #pragma unroll 4
    for (int i = 0; i < 64; ++i) {
        float4 v = p[(long)(way * 64 + i) * 1024 + eg];
        acc.x += v.x; acc.y += v.y; acc.z += v.z; acc.w += v.w;
    }
    atomicAdd(&S[eg * 4 + 0], acc.x);
    atomicAdd(&S[eg * 4 + 1], acc.y);
    atomicAdd(&S[eg * 4 + 2], acc.z);
    atomicAdd(&S[eg * 4 + 3], acc.w);
}

// ---------------- Kernel B: per-trunk  out = Q (K^T V) S --------------------
// One trunk per 256-thread block. K,V staged transposed at stride 136; all
// MFMA fragments via ds_read_b128. G overlays KT, HT overlays VT after use.
// LDS 44032 B -> 3 blocks/CU.
#define KT_OFF 0                  // [64][136] K^T; later G[a][b] ([64][72])
#define VT_OFF (64 * KV_T)        // [64][136] V^T; later HT[c][a]
#define ST_OFF (2 * 64 * KV_T)    // [64][72]  S^T bf16
#define LDS_ELEMS (2 * 64 * KV_T + 64 * P_S)   // 22016 u16 = 44032 B

__global__ __launch_bounds__(256, 3) void trunk_kernel(const float* __restrict__ Q,
                                                       const float* __restrict__ K,
                                                       const float* __restrict__ V,
                                                       const float* __restrict__ S,
                                                       float* __restrict__ out) {
    __shared__ __align__(16) u16 lds[LDS_ELEMS];
    u16* KT  = lds + KT_OFF;
    u16* VT  = lds + VT_OFF;
    u16* STb = lds + ST_OFF;
    u16* Gb  = lds + KT_OFF;
    u16* HTb = lds + VT_OFF;

    const int t    = threadIdx.x;
    const int lane = t & 63;
    const int wave = t >> 6;
    const int l15  = lane & 15;
    const int quad = lane >> 4;
    const long tb  = (long)blockIdx.x * (TRUNK * DD);

    // ---- prefetch Q fragments (used only in stage 3; hides global latency) --
    F8 a3[2][2];   // [kt][mi]
    #pragma unroll
    for (int kt = 0; kt < 2; ++kt)
        #pragma unroll
        for (int mi = 0; mi < 2; ++mi) {
            const int r = (wave * 2 + mi) * 16 + l15;
            const float* qp = Q + tb + r * 64 + kt * 32 + quad * 8;
            float4 q0 = *(const float4*)qp;
            float4 q1 = *(const float4*)(qp + 4);
            a3[kt][mi].q[0] = pack2(q0.x, q0.y);
            a3[kt][mi].q[1] = pack2(q0.z, q0.w);
            a3[kt][mi].q[2] = pack2(q1.x, q1.y);
            a3[kt][mi].q[3] = pack2(q1.z, q1.w);
        }

    // ---- stage K^T, V^T, S^T into LDS ---------------------------------------
    stage_T(K, tb, KT, t);
    stage_T(V, tb, VT, t);
    #pragma unroll
    for (int i = 0; i < 4; ++i) {
        int f4 = i * 256 + t;               // 1024 float4 of S (64x64 fp32)
        int b = f4 >> 4, c = (f4 & 15) << 2;
        float4 s4 = ((const float4*)S)[f4];
        const float* sp = (const float*)&s4;
        #pragma unroll
        for (int j = 0; j < 4; ++j) STb[(c + j) * P_S + b] = f2bf(sp[j]);
    }
    __syncthreads();

    // ---- stage 1: C1 = V^T K (m = V-col b, n = K-col a, k = row r) ----------
    const int mt0 = (wave >> 1) << 1;       // 2x2 tile quadrant per wave
    const int nt0 = (wave & 1) << 1;
    f32x4 gacc[2][2] = {};
    #pragma unroll
    for (int kt = 0; kt < 4; ++kt) {
        const int rbase = kt * 32 + quad * 8;
        F8 af[2], bf[2];
        #pragma unroll
        for (int mi = 0; mi < 2; ++mi)
            af[mi].q = *(const u32x4*)&VT[((mt0 + mi) * 16 + l15) * KV_T + rbase];
        #pragma unroll
        for (int ni = 0; ni < 2; ++ni)
            bf[ni].q = *(const u32x4*)&KT[((nt0 + ni) * 16 + l15) * KV_T + rbase];
        #pragma unroll
        for (int mi = 0; mi < 2; ++mi)
            #pragma unroll
            for (int ni = 0; ni < 2; ++ni)
                gacc[mi][ni] = __builtin_amdgcn_mfma_f32_16x16x32_bf16(
                    af[mi].v, bf[ni].v, gacc[mi][ni], 0, 0, 0);
    }
    __syncthreads();   // all KT/VT reads done before overlaying G

    // C1[b][a] = G[a][b]; C-frag row=4*quad+reg, col=l15 -> write G natural
    #pragma unroll
    for (int mi = 0; mi < 2; ++mi)
        #pragma unroll
        for (int ni = 0; ni < 2; ++ni) {
            const int ga  = (nt0 + ni) * 16 + l15;
            const int gb0 = (mt0 + mi) * 16 + quad * 4;
            const float* g = (const float*)&gacc[mi][ni];
            u32x2 w; w[0] = pack2(g[0], g[1]); w[1] = pack2(g[2], g[3]);
            *(u32x2*)&Gb[ga * P_S + gb0] = w;
        }
    __syncthreads();

    // ---- stage 2: H = G @ S  (A = G rows, B = ST rows) ----------------------
    f32x4 hacc[2][2] = {};
    #pragma unroll
    for (int kt = 0; kt < 2; ++kt) {
        const int kb = kt * 32 + quad * 8;
        F8 a2[2], b2[2];
        #pragma unroll
        for (int mi = 0; mi < 2; ++mi)
            a2[mi].q = *(const u32x4*)&Gb[((mt0 + mi) * 16 + l15) * P_S + kb];
        #pragma unroll
        for (int ni = 0; ni < 2; ++ni)
            b2[ni].q = *(const u32x4*)&STb[((nt0 + ni) * 16 + l15) * P_S + kb];
        #pragma unroll
        for (int mi = 0; mi < 2; ++mi)
            #pragma unroll
            for (int ni = 0; ni < 2; ++ni)
                hacc[mi][ni] = __builtin_amdgcn_mfma_f32_16x16x32_bf16(
                    a2[mi].v, b2[ni].v, hacc[mi][ni], 0, 0, 0);
    }
    // write HT[c][a] into VT region (stage-1 reads fenced by prior barrier)
    #pragma unroll
    for (int mi = 0; mi < 2; ++mi)
        #pragma unroll
        for (int ni = 0; ni < 2; ++ni) {
            const int hc  = (nt0 + ni) * 16 + l15;
            const int ha0 = (mt0 + mi) * 16 + quad * 4;
            const float* h = (const float*)&hacc[mi][ni];
            u32x2 w; w[0] = pack2(h[0], h[1]); w[1] = pack2(h[2], h[3]);
            *(u32x2*)&HTb[hc * P_S + ha0] = w;
        }
    __syncthreads();

    // ---- stage 3: out = Q @ H  (A = prefetched Q, B = HT rows) --------------
    f32x4 oacc[2][4] = {};
    #pragma unroll
    for (int kt = 0; kt < 2; ++kt) {
        const int ka = kt * 32 + quad * 8;
        #pragma unroll
        for (int ni = 0; ni < 4; ++ni) {
            F8 bb;
            bb.q = *(const u32x4*)&HTb[(ni * 16 + l15) * P_S + ka];
            #pragma unroll
            for (int mi = 0; mi < 2; ++mi)
                oacc[mi][ni] = __builtin_amdgcn_mfma_f32_16x16x32_bf16(
                    a3[kt][mi].v, bb.v, oacc[mi][ni], 0, 0, 0);
        }
    }
    #pragma unroll
    for (int mi = 0; mi < 2; ++mi)
        #pragma unroll
        for (int ni = 0; ni < 4; ++ni) {
            const int row0 = (wave * 2 + mi) * 16 + quad * 4;
            const int col  = ni * 16 + l15;
            const float* o = (const float*)&oacc[mi][ni];
            #pragma unroll
            for (int reg = 0; reg < 4; ++reg)
                out[tb + (long)(row0 + reg) * 64 + col] = o[reg];
        }
}

extern "C" void kernel_launch(void* const* d_in, const int* in_sizes, int n_in,
                              void* d_out, int out_size, void* d_ws, size_t ws_size,
                              hipStream_t stream) {
    const float* Q = (const float*)d_in[0];
    const float* K = (const float*)d_in[1];
    const float* V = (const float*)d_in[2];
    float* out = (float*)d_out;
    float* S   = (float*)d_ws;                     // 4096 fp32 = 16 KB only

    const int n = in_sizes[0] / DD;                // 262144 rows
    // partials in the tail of d_out (8 MB of 64 MB); consumed by s_reduce,
    // then fully overwritten by trunk_kernel (stream-serialized).
    float* P = out + ((long)out_size - (long)NPART * 4096);

    hipMemsetAsync(S, 0, DD * DD * sizeof(float), stream);
    s_partial<<<NPART, 256, 0, stream>>>(K, V, P);
    s_reduce<<<32, 256, 0, stream>>>(P, S);
    trunk_kernel<<<n / TRUNK, 256, 0, stream>>>(Q, K, V, S, out);
}